// Round 7
// baseline (749.080 us; speedup 1.0000x reference)
//
#include <hip/hip_runtime.h>

#define NN 100000
#define NE 3200000
#define NG 2000
#define FIN 14
#define HD 64
#define NC 2

#define NBUK 256
#define BNODES 391      // 256*391 = 100096 >= NN
#define P1E 4096        // edges per pass-1 block
#define BUFCAP 13312    // pass-2 LDS csr slice capacity (mean 12500, +7 sigma)

#define NT 8            // src tiles
#define TNODES 12500    // nodes per src tile (8*12500 = 100000 exact)
#define NCELL (BNODES * NT)   // 3128
#define NCELLP 3328           // 256*13 padded
#define NPW 25          // nodes per wave in layerH (1000 blocks * 4 waves * 25 = 100000 exact)

typedef unsigned int uint;

__device__ __forceinline__ uint pack2bf16(float a, float b) {
    uint ua = __float_as_uint(a), ub = __float_as_uint(b);
    ua = (ua + 0x7FFFu + ((ua >> 16) & 1u)) >> 16;
    ub = (ub + 0x7FFFu + ((ub >> 16) & 1u)) >> 16;
    return ua | (ub << 16);
}
__device__ __forceinline__ float bflo(uint u) { return __uint_as_float(u << 16); }
__device__ __forceinline__ float bfhi(uint u) { return __uint_as_float(u & 0xFFFF0000u); }

// ---------------- bucket histogram (LDS-privatized) ----------------

__global__ __launch_bounds__(256) void k_hist_bucket(const int* __restrict__ dst,
                                                     int* __restrict__ bkcnt) {
    __shared__ int cnt[NBUK];
    int t = threadIdx.x;
    cnt[t] = 0;
    __syncthreads();
    int e0 = blockIdx.x * P1E;
    int m = NE - e0; if (m > P1E) m = P1E;
    for (int e = t; e < m; e += 256) atomicAdd(&cnt[dst[e0 + e] / BNODES], 1);
    __syncthreads();
    if (cnt[t] > 0) atomicAdd(&bkcnt[t], cnt[t]);
}

// exclusive scan of 256 bucket counts -> bbase[257]; also init bcur
__global__ void k_scanb(const int* __restrict__ bkcnt, int* __restrict__ bbase,
                        int* __restrict__ bcur) {
    __shared__ int tmp[NBUK];
    int t = threadIdx.x;
    int v = bkcnt[t];
    tmp[t] = v;
    __syncthreads();
    for (int off = 1; off < NBUK; off <<= 1) {
        int u = (t >= off) ? tmp[t - off] : 0;
        __syncthreads();
        tmp[t] += u;
        __syncthreads();
    }
    int excl = tmp[t] - v;
    bbase[t] = excl;
    bcur[t] = excl;
    if (t == NBUK - 1) bbase[NBUK] = tmp[t];
}

// graph boundaries from sorted batch
__global__ void k_gbounds(const int* __restrict__ batch, int* __restrict__ gstart,
                          int* __restrict__ gend) {
    int i = blockIdx.x * blockDim.x + threadIdx.x;
    if (i < NN) {
        int b = batch[i];
        if (i == 0 || batch[i - 1] != b) gstart[b] = i;
        if (i == NN - 1 || batch[i + 1] != b) gend[b] = i + 1;
    }
}

// pass 1: block-local binning by dst-bucket; packed (src | localdst<<17) run writes
__global__ __launch_bounds__(256) void k_pass1(
    const int* __restrict__ src, const int* __restrict__ dst,
    int* __restrict__ bcur, int* __restrict__ pairs) {
    __shared__ int cnt[NBUK];
    __shared__ int scanb[NBUK + 1];
    __shared__ int cur[NBUK];
    __shared__ int gbase[NBUK];
    __shared__ int pbuf[P1E];
    __shared__ unsigned char bsl[P1E];
    int t = threadIdx.x;
    int e0 = blockIdx.x * P1E;
    int m = NE - e0; if (m > P1E) m = P1E;
    cnt[t] = 0;
    __syncthreads();
    int ds[16], ss[16], bk[16];
#pragma unroll
    for (int j = 0; j < 16; ++j) {
        int e = t + j * 256;
        if (e < m) {
            ds[j] = dst[e0 + e];
            ss[j] = src[e0 + e];
            bk[j] = ds[j] / BNODES;
            atomicAdd(&cnt[bk[j]], 1);
        } else bk[j] = -1;
    }
    __syncthreads();
    int v = cnt[t];
    scanb[t] = v;
    __syncthreads();
    for (int off = 1; off < 256; off <<= 1) {
        int u = (t >= off) ? scanb[t - off] : 0;
        __syncthreads();
        scanb[t] += u;
        __syncthreads();
    }
    int excl = scanb[t] - v;
    scanb[t] = excl;
    cur[t] = excl;
    if (t == 255) scanb[256] = excl + v;
    __syncthreads();
#pragma unroll
    for (int j = 0; j < 16; ++j) {
        if (bk[j] >= 0) {
            int p = atomicAdd(&cur[bk[j]], 1);
            pbuf[p] = ss[j] | ((ds[j] - bk[j] * BNODES) << 17);
            bsl[p] = (unsigned char)bk[j];
        }
    }
    int cb = scanb[t + 1] - scanb[t];
    if (cb > 0) gbase[t] = atomicAdd(&bcur[t], cb);
    __syncthreads();
    for (int s = t; s < m; s += 256) {
        int b = bsl[s];
        pairs[gbase[b] + (s - scanb[b])] = pbuf[s];
    }
}

// pass 2: one block per bucket. Per-(node, src-tile) histogram -> scan ->
// deg/rs/rs9 out, tile-sorted scatter -> coalesced csr out.
__global__ __launch_bounds__(256) void k_pass2(
    const int* __restrict__ pairs, const int* __restrict__ bbase,
    int* __restrict__ deg, int* __restrict__ rs, int* __restrict__ rs9,
    int* __restrict__ csr) {
    __shared__ int buf2[BUFCAP];     // 52 KB
    __shared__ int cnt[NCELLP];
    __shared__ int off[NCELLP + 1];
    __shared__ int cur[NCELLP];
    __shared__ int s1[256];
    int b = blockIdx.x;
    int n0 = b * BNODES;
    if (n0 >= NN) return;
    int nlocal = NN - n0; if (nlocal > BNODES) nlocal = BNODES;
    int t = threadIdx.x;
    int base = bbase[b];
    int m = bbase[b + 1] - base;
    for (int k = t; k < NCELLP; k += 256) cnt[k] = 0;
    __syncthreads();
    for (int s = t; s < m; s += 256) {
        int pk = pairs[base + s];
        int ln = (uint)pk >> 17;
        int sr = pk & 0x1FFFF;
        atomicAdd(&cnt[ln * NT + sr / TNODES], 1);
    }
    __syncthreads();
    // exclusive scan over NCELLP cells: thread t owns [13t, 13t+13)
    int loc[13];
    int run = 0;
#pragma unroll
    for (int k = 0; k < 13; ++k) { loc[k] = run; run += cnt[t * 13 + k]; }
    s1[t] = run;
    __syncthreads();
    for (int o = 1; o < 256; o <<= 1) {
        int u = (t >= o) ? s1[t - o] : 0;
        __syncthreads();
        s1[t] += u;
        __syncthreads();
    }
    int excl = s1[t] - run;
#pragma unroll
    for (int k = 0; k < 13; ++k) {
        int val = excl + loc[k];
        off[t * 13 + k] = val;
        cur[t * 13 + k] = val;
    }
    if (t == 0) off[NCELLP] = m;
    __syncthreads();
    // emit deg, rs, rs9
    for (int i = t; i < nlocal; i += 256) {
        int o0 = off[i * NT];
        int o8 = off[(i + 1) * NT];
        deg[n0 + i] = o8 - o0;
        rs[n0 + i] = base + o0;
#pragma unroll
        for (int st = 0; st < NT; ++st) rs9[(size_t)(n0 + i) * 9 + st] = base + off[i * NT + st];
        rs9[(size_t)(n0 + i) * 9 + 8] = base + o8;
    }
    bool fits = (m <= BUFCAP);
    if (fits) {
        for (int s = t; s < m; s += 256) {
            int pk = pairs[base + s];     // re-read, L2-hot
            int ln = (uint)pk >> 17, sr = pk & 0x1FFFF;
            int p = atomicAdd(&cur[ln * NT + sr / TNODES], 1);
            buf2[p] = sr;
        }
        __syncthreads();
        for (int s = t; s < m; s += 256) csr[base + s] = buf2[s];
    } else {
        for (int s = t; s < m; s += 256) {
            int pk = pairs[base + s];
            int ln = (uint)pk >> 17, sr = pk & 0x1FFFF;
            int p = atomicAdd(&cur[ln * NT + sr / TNODES], 1);
            csr[base + p] = sr;
        }
    }
}

// ---------------- x prepack: [N,14] f32 -> [N,16] bf16 (8 uints/row) ----------------

__global__ void k_packx(const float* __restrict__ x, uint* __restrict__ xb) {
    int t = blockIdx.x * blockDim.x + threadIdx.x;
    if (t < NN * 8) {
        int row = t >> 3, q = t & 7;
        int j0 = 2 * q, j1 = 2 * q + 1;
        float f0 = (j0 < FIN) ? x[row * FIN + j0] : 0.f;
        float f1 = (j1 < FIN) ? x[row * FIN + j1] : 0.f;
        xb[t] = pack2bf16(f0, f1);
    }
}

// ---------------- Layer 1: xb16 -> hb16 (unchanged from R6; tile-order agnostic) ----------------

__global__ __launch_bounds__(256, 6) void k_layer1(
    const float* __restrict__ x, const uint* __restrict__ xb, uint* __restrict__ hbout,
    const float* __restrict__ Wl, const float* __restrict__ Wr, const float* __restrict__ b,
    const int* __restrict__ rs, const int* __restrict__ deg, const int* __restrict__ csr) {
    __shared__ float2 sW[FIN][HD];
    __shared__ float sb[HD];
    __shared__ float2 sAH[4][16];
    for (int i = threadIdx.x; i < FIN * HD; i += 256) {
        int k = i >> 6, j = i & 63;
        sW[k][j] = make_float2(Wl[i], Wr[i]);
    }
    if (threadIdx.x < HD) sb[threadIdx.x] = b[threadIdx.x];
    __syncthreads();
    int lane = threadIdx.x & 63, wid = threadIdx.x >> 6;
    int sub = lane >> 3;
    int fq = lane & 7;
    int ngroups = (NN + 3) / 4;
    for (int g = blockIdx.x; g < ngroups; g += gridDim.x) {
        int n = g * 4 + wid;
        bool act = n < NN;
        if (act) {
            int s0 = rs[n], d = deg[n];
            float xv = (lane < FIN) ? x[n * FIN + lane] : 0.f;
            float2 a0 = make_float2(0.f, 0.f), a1 = a0, a2 = a0, a3 = a0;
            float2 a4 = a0, a5 = a0, a6 = a0, a7 = a0;
            for (int base = 0; base < d; base += 64) {
                int rem = d - base; if (rem > 64) rem = 64;
                int idxv = (lane < rem) ? csr[s0 + base + lane] : 0;
                int j = 0;
                for (; j + 64 <= rem; j += 64) {
                    int i0 = __shfl(idxv, j + 0 + sub);
                    int i1 = __shfl(idxv, j + 8 + sub);
                    int i2 = __shfl(idxv, j + 16 + sub);
                    int i3 = __shfl(idxv, j + 24 + sub);
                    int i4 = __shfl(idxv, j + 32 + sub);
                    int i5 = __shfl(idxv, j + 40 + sub);
                    int i6 = __shfl(idxv, j + 48 + sub);
                    int i7 = __shfl(idxv, j + 56 + sub);
                    uint u;
                    u = xb[(size_t)i0 * 8 + fq]; a0.x += bflo(u); a0.y += bfhi(u);
                    u = xb[(size_t)i1 * 8 + fq]; a1.x += bflo(u); a1.y += bfhi(u);
                    u = xb[(size_t)i2 * 8 + fq]; a2.x += bflo(u); a2.y += bfhi(u);
                    u = xb[(size_t)i3 * 8 + fq]; a3.x += bflo(u); a3.y += bfhi(u);
                    u = xb[(size_t)i4 * 8 + fq]; a4.x += bflo(u); a4.y += bfhi(u);
                    u = xb[(size_t)i5 * 8 + fq]; a5.x += bflo(u); a5.y += bfhi(u);
                    u = xb[(size_t)i6 * 8 + fq]; a6.x += bflo(u); a6.y += bfhi(u);
                    u = xb[(size_t)i7 * 8 + fq]; a7.x += bflo(u); a7.y += bfhi(u);
                }
                for (; j + 8 <= rem; j += 8) {
                    int i0 = __shfl(idxv, j + sub);
                    uint u = xb[(size_t)i0 * 8 + fq];
                    a0.x += bflo(u); a0.y += bfhi(u);
                }
                if (j < rem) {
                    int i0 = __shfl(idxv, j + sub);
                    if (sub < rem - j) {
                        uint u = xb[(size_t)i0 * 8 + fq];
                        a0.x += bflo(u); a0.y += bfhi(u);
                    }
                }
            }
            a0.x += a1.x + a2.x + a3.x + a4.x + a5.x + a6.x + a7.x;
            a0.y += a1.y + a2.y + a3.y + a4.y + a5.y + a6.y + a7.y;
            for (int off = 8; off <= 32; off <<= 1) {
                a0.x += __shfl_xor(a0.x, off);
                a0.y += __shfl_xor(a0.y, off);
            }
            float inv = 1.0f / (float)(d > 1 ? d : 1);
            float e0 = __shfl(a0.x, lane >> 1);
            float e1 = __shfl(a0.y, lane >> 1);
            float sel = (lane & 1) ? e1 : e0;
            if (lane < 16) sAH[wid][lane] = make_float2((lane < FIN) ? sel * inv : 0.f, xv);
        }
        float out = sb[lane];
#pragma unroll
        for (int k = 0; k < FIN; ++k) {
            float2 w = sW[k][lane];
            float2 ah = sAH[wid][k];
            out += ah.x * w.x + ah.y * w.y;
        }
        out = fmaxf(out, 0.f);
        float o2 = __shfl_xor(out, 1);
        if (act && !(lane & 1)) hbout[(size_t)n * 32 + (lane >> 1)] = pack2bf16(out, o2);
    }
}

// ---------------- H layers: src-tile phased gather, register partials ----------------

template <bool FUSEZ>
__global__ __launch_bounds__(256, 4) void k_layerH(
    const uint* __restrict__ hbin, uint* __restrict__ hbout,
    const float* __restrict__ Wl, const float* __restrict__ Wr, const float* __restrict__ b,
    const float* __restrict__ W4l, float* __restrict__ z,
    const int* __restrict__ rs9, const int* __restrict__ csr) {
    __shared__ uint sWp[HD][HD];        // {Wl,Wr} packed bf16: 16 KB
    __shared__ float sb[HD], sW4l[HD * NC];
    __shared__ uint sSp[4][NPW][32];    // per-wave agg spill (bf16 pairs): 12.8 KB
    __shared__ float2 sAH[4][HD];
    for (int i = threadIdx.x; i < HD * HD; i += 256) {
        int k = i >> 6, j = i & 63;
        sWp[k][j] = pack2bf16(Wl[i], Wr[i]);
    }
    if (threadIdx.x < HD) sb[threadIdx.x] = b[threadIdx.x];
    if (FUSEZ && threadIdx.x < HD * NC) sW4l[threadIdx.x] = W4l[threadIdx.x];
    __syncthreads();
    int lane = threadIdx.x & 63;
    int wid = __builtin_amdgcn_readfirstlane(threadIdx.x >> 6);   // wave-uniform SGPR
    int sub = lane >> 5;     // 2 edges in flight per j-step pair
    int q = lane & 31;       // uint index within 32-uint row
    int n0 = (blockIdx.x * 4 + wid) * NPW;   // uniform -> rs9 reads become s_loads
    float2 acc[NPW];
#pragma unroll
    for (int i = 0; i < NPW; ++i) acc[i] = make_float2(0.f, 0.f);
    // phased sweep: all co-resident blocks walk src-tiles together -> L2-resident window
    for (int st = 0; st < NT; ++st) {
#pragma unroll
        for (int i = 0; i < NPW; ++i) {
            int n = n0 + i;
            if (n < NN) {
                int s0 = rs9[(size_t)n * 9 + st];
                int e  = rs9[(size_t)n * 9 + st + 1];
                int c = e - s0;
                for (int bs = 0; bs < c; bs += 64) {
                    int rem = c - bs; if (rem > 64) rem = 64;
                    int idx = (lane < rem) ? csr[s0 + bs + lane] : 0;
                    for (int j = 0; j < rem; j += 4) {
                        int sA = __shfl(idx, j + sub);
                        int sB = __shfl(idx, j + 2 + sub);
                        uint uA = hbin[(uint)sA * 32u + q];
                        uint uB = hbin[(uint)sB * 32u + q];
                        if (j + sub < rem)     { acc[i].x += bflo(uA); acc[i].y += bfhi(uA); }
                        if (j + 2 + sub < rem) { acc[i].x += bflo(uB); acc[i].y += bfhi(uB); }
                    }
                }
            }
        }
    }
    // combine halves, scale, spill to LDS as bf16
#pragma unroll
    for (int i = 0; i < NPW; ++i) {
        int n = n0 + i;
        float ax = acc[i].x + __shfl_xor(acc[i].x, 32);
        float ay = acc[i].y + __shfl_xor(acc[i].y, 32);
        if (n < NN) {
            int d = rs9[(size_t)n * 9 + 8] - rs9[(size_t)n * 9];
            float inv = 1.0f / (float)(d > 1 ? d : 1);
            if (lane < 32) sSp[wid][i][q] = pack2bf16(ax * inv, ay * inv);
        }
    }
    // dense phase (dynamic node loop; agg read back from LDS)
    for (int i = 0; i < NPW; ++i) {
        int n = n0 + i;
        if (n >= NN) break;
        uint au = sSp[wid][i][lane >> 1];
        float aggk = (lane & 1) ? bfhi(au) : bflo(au);
        uint hu = hbin[(uint)n * 32u + (lane >> 1)];
        float hv = (lane & 1) ? bfhi(hu) : bflo(hu);
        sAH[wid][lane] = make_float2(aggk, hv);
        float outA = sb[lane], outB = 0.f;
#pragma unroll 8
        for (int k = 0; k < HD; ++k) {
            uint wu = sWp[k][lane];
            float2 ah = sAH[wid][k];
            outA += ah.x * bflo(wu);
            outB += ah.y * bfhi(wu);
        }
        float out = fmaxf(outA + outB, 0.f);
        float o2 = __shfl_xor(out, 1);
        if (!(lane & 1)) hbout[(uint)n * 32u + (lane >> 1)] = pack2bf16(out, o2);
        if (FUSEZ) {
            float r0 = out * sW4l[lane * NC + 0];
            float r1 = out * sW4l[lane * NC + 1];
            for (int off = 32; off; off >>= 1) {
                r0 += __shfl_xor(r0, off);
                r1 += __shfl_xor(r1, off);
            }
            if (lane == 0) ((float2*)z)[n] = make_float2(r0, r1);
        }
    }
}

// ---------------- Layer 4 + graph pooling sum ----------------

__global__ __launch_bounds__(256) void k_pool(
    const uint* __restrict__ h3, const float* __restrict__ z,
    const float* __restrict__ W4r, const float* __restrict__ b4,
    const int* __restrict__ rs, const int* __restrict__ deg, const int* __restrict__ csr,
    const int* __restrict__ batch, float* __restrict__ gsum) {
    __shared__ float sW[HD * NC];
    if (threadIdx.x < HD * NC) sW[threadIdx.x] = W4r[threadIdx.x];
    __syncthreads();
    const float2* z2 = (const float2*)z;
    int lane = threadIdx.x & 63, wid = threadIdx.x >> 6;
    int stride = gridDim.x * 4;
    for (int n = blockIdx.x * 4 + wid; n < NN; n += stride) {
        float r0 = 0.f, r1 = 0.f;
        if (lane < 32) {
            uint u = h3[(size_t)n * 32 + lane];
            float f0 = bflo(u), f1 = bfhi(u);
            r0 = f0 * sW[(2 * lane) * NC + 0] + f1 * sW[(2 * lane + 1) * NC + 0];
            r1 = f0 * sW[(2 * lane) * NC + 1] + f1 * sW[(2 * lane + 1) * NC + 1];
        }
        int s0 = rs[n], d = deg[n];
        float a0 = 0.f, a1 = 0.f;
        for (int j = lane; j < d; j += 64) {
            int s = csr[s0 + j];
            float2 zv = z2[s];
            a0 += zv.x;
            a1 += zv.y;
        }
        for (int off = 32; off; off >>= 1) {
            r0 += __shfl_xor(r0, off);
            r1 += __shfl_xor(r1, off);
            a0 += __shfl_xor(a0, off);
            a1 += __shfl_xor(a1, off);
        }
        if (lane == 0) {
            float inv = 1.0f / (float)(d > 1 ? d : 1);
            float o0 = a0 * inv + r0 + b4[0];
            float o1 = a1 * inv + r1 + b4[1];
            int gg = batch[n];
            atomicAdd(&gsum[gg * 2 + 0], o0);
            atomicAdd(&gsum[gg * 2 + 1], o1);
        }
    }
}

__global__ void k_final(const float* __restrict__ gsum, const int* __restrict__ gstart,
                        const int* __restrict__ gend, float* __restrict__ out) {
    int g = blockIdx.x * blockDim.x + threadIdx.x;
    if (g < NG) {
        int cnt = gend[g] - gstart[g];
        float inv = 1.0f / (float)(cnt > 1 ? cnt : 1);
        float p0 = gsum[g * 2 + 0] * inv;
        float p1 = gsum[g * 2 + 1] * inv;
        float m = fmaxf(p0, p1);
        float lse = m + logf(expf(p0 - m) + expf(p1 - m));
        out[g * 2 + 0] = p0 - lse;
        out[g * 2 + 1] = p1 - lse;
    }
}

// ---------------- launch ----------------

extern "C" void kernel_launch(void* const* d_in, const int* in_sizes, int n_in,
                              void* d_out, int out_size, void* d_ws, size_t ws_size,
                              hipStream_t stream) {
    const float* x   = (const float*)d_in[0];
    const float* W1l = (const float*)d_in[1];
    const float* W1r = (const float*)d_in[2];
    const float* b1  = (const float*)d_in[3];
    const float* W2l = (const float*)d_in[4];
    const float* W2r = (const float*)d_in[5];
    const float* b2  = (const float*)d_in[6];
    const float* W3l = (const float*)d_in[7];
    const float* W3r = (const float*)d_in[8];
    const float* b3  = (const float*)d_in[9];
    const float* W4l = (const float*)d_in[10];
    const float* W4r = (const float*)d_in[11];
    const float* b4  = (const float*)d_in[12];
    const int* ei    = (const int*)d_in[13];
    const int* batch = (const int*)d_in[14];
    const int* src = ei;
    const int* dst = ei + NE;
    float* out = (float*)d_out;

    char* w = (char*)d_ws;
    int* deg    = (int*)w; w += (size_t)NN * 4;
    int* rs     = (int*)w; w += (size_t)NN * 4;
    int* csr    = (int*)w; w += (size_t)NE * 4;
    int* rs9    = (int*)w; w += (size_t)NN * 9 * 4;
    int* gstart = (int*)w; w += (size_t)NG * 4;
    int* gend   = (int*)w; w += (size_t)NG * 4;
    int* bkcnt  = (int*)w; w += NBUK * 4;
    int* bbase  = (int*)w; w += (NBUK + 1) * 4;
    int* bcur   = (int*)w; w += NBUK * 4;
    w = (char*)(((uintptr_t)w + 255) & ~(uintptr_t)255);
    uint* xb    = (uint*)w; w += (size_t)NN * 8 * 4;
    uint* hbA   = (uint*)w; w += (size_t)NN * 32 * 4;
    uint* hbB   = (uint*)w; w += (size_t)NN * 32 * 4;
    float* z    = (float*)w; w += (size_t)NN * NC * 4;
    float* gsum = (float*)w; w += (size_t)NG * NC * 4;
    int* pairs = (int*)hbB;  // alias: NE*4 == NN*32*4 bytes; dead before layer 2 writes hbB

    const int P1B = (NE + P1E - 1) / P1E;  // 782

    hipMemsetAsync(bkcnt, 0, NBUK * 4, stream);
    hipMemsetAsync(gstart, 0, (size_t)NG * 4, stream);
    hipMemsetAsync(gend, 0, (size_t)NG * 4, stream);
    hipMemsetAsync(gsum, 0, (size_t)NG * NC * 4, stream);

    k_hist_bucket<<<P1B, 256, 0, stream>>>(dst, bkcnt);
    k_packx<<<(NN * 8 + 255) / 256, 256, 0, stream>>>(x, xb);
    k_gbounds<<<(NN + 255) / 256, 256, 0, stream>>>(batch, gstart, gend);
    k_scanb<<<1, NBUK, 0, stream>>>(bkcnt, bbase, bcur);
    k_pass1<<<P1B, 256, 0, stream>>>(src, dst, bcur, pairs);
    k_pass2<<<NBUK, 256, 0, stream>>>(pairs, bbase, deg, rs, rs9, csr);

    k_layer1<<<1536, 256, 0, stream>>>(x, xb, hbA, W1l, W1r, b1, rs, deg, csr);
    k_layerH<false><<<1000, 256, 0, stream>>>(hbA, hbB, W2l, W2r, b2, nullptr, nullptr, rs9, csr);
    k_layerH<true><<<1000, 256, 0, stream>>>(hbB, hbA, W3l, W3r, b3, W4l, z, rs9, csr);
    k_pool<<<2048, 256, 0, stream>>>(hbA, z, W4r, b4, rs, deg, csr, batch, gsum);
    k_final<<<(NG + 255) / 256, 256, 0, stream>>>(gsum, gstart, gend, out);
}

// Round 9
// 444.220 us; speedup vs baseline: 1.6863x; 1.6863x over previous
//
#include <hip/hip_runtime.h>
#include <hip/hip_fp16.h>

#define NN 100000
#define NE 3200000
#define NG 2000
#define FIN 14
#define HD 64
#define NC 2

#define NBUK 256
#define BNODES 391      // 256*391 = 100096 >= NN
#define P1E 4096        // edges per pass-1 block
#define BUFCAP 13312    // pass-2 LDS csr slice capacity (mean 12500, +7 sigma)

typedef unsigned int uint;

__device__ __forceinline__ __half2 u2h(uint u) {
    union { uint u; __half2 h; } c; c.u = u; return c.h;
}
__device__ __forceinline__ uint h2u(__half2 h) {
    union { __half2 h; uint u; } c; c.h = h; return c.u;
}
__device__ __forceinline__ uint pkh(float a, float b) {
    return h2u(__floats2half2_rn(a, b));
}

// ---------------- bucket histogram (LDS-privatized) ----------------

__global__ __launch_bounds__(256) void k_hist_bucket(const int* __restrict__ dst,
                                                     int* __restrict__ bkcnt) {
    __shared__ int cnt[NBUK];
    int t = threadIdx.x;
    cnt[t] = 0;
    __syncthreads();
    int e0 = blockIdx.x * P1E;
    int m = NE - e0; if (m > P1E) m = P1E;
    for (int e = t; e < m; e += 256) atomicAdd(&cnt[dst[e0 + e] / BNODES], 1);
    __syncthreads();
    if (cnt[t] > 0) atomicAdd(&bkcnt[t], cnt[t]);
}

// exclusive scan of 256 bucket counts -> bbase[257]; also init bcur
__global__ void k_scanb(const int* __restrict__ bkcnt, int* __restrict__ bbase,
                        int* __restrict__ bcur) {
    __shared__ int tmp[NBUK];
    int t = threadIdx.x;
    int v = bkcnt[t];
    tmp[t] = v;
    __syncthreads();
    for (int off = 1; off < NBUK; off <<= 1) {
        int u = (t >= off) ? tmp[t - off] : 0;
        __syncthreads();
        tmp[t] += u;
        __syncthreads();
    }
    int excl = tmp[t] - v;
    bbase[t] = excl;
    bcur[t] = excl;
    if (t == NBUK - 1) bbase[NBUK] = tmp[t];
}

// graph boundaries from sorted batch
__global__ void k_gbounds(const int* __restrict__ batch, int* __restrict__ gstart,
                          int* __restrict__ gend) {
    int i = blockIdx.x * blockDim.x + threadIdx.x;
    if (i < NN) {
        int b = batch[i];
        if (i == 0 || batch[i - 1] != b) gstart[b] = i;
        if (i == NN - 1 || batch[i + 1] != b) gend[b] = i + 1;
    }
}

// pass 1: block-local binning by dst-bucket; packed (src | localdst<<17) run writes
__global__ __launch_bounds__(256) void k_pass1(
    const int* __restrict__ src, const int* __restrict__ dst,
    int* __restrict__ bcur, int* __restrict__ pairs) {
    __shared__ int cnt[NBUK];
    __shared__ int scanb[NBUK + 1];
    __shared__ int cur[NBUK];
    __shared__ int gbase[NBUK];
    __shared__ int pbuf[P1E];
    __shared__ unsigned char bsl[P1E];
    int t = threadIdx.x;
    int e0 = blockIdx.x * P1E;
    int m = NE - e0; if (m > P1E) m = P1E;
    cnt[t] = 0;
    __syncthreads();
    int ds[16], ss[16], bk[16];
#pragma unroll
    for (int j = 0; j < 16; ++j) {
        int e = t + j * 256;
        if (e < m) {
            ds[j] = dst[e0 + e];
            ss[j] = src[e0 + e];
            bk[j] = ds[j] / BNODES;
            atomicAdd(&cnt[bk[j]], 1);
        } else bk[j] = -1;
    }
    __syncthreads();
    int v = cnt[t];
    scanb[t] = v;
    __syncthreads();
    for (int off = 1; off < 256; off <<= 1) {
        int u = (t >= off) ? scanb[t - off] : 0;
        __syncthreads();
        scanb[t] += u;
        __syncthreads();
    }
    int excl = scanb[t] - v;
    scanb[t] = excl;
    cur[t] = excl;
    if (t == 255) scanb[256] = excl + v;
    __syncthreads();
#pragma unroll
    for (int j = 0; j < 16; ++j) {
        if (bk[j] >= 0) {
            int p = atomicAdd(&cur[bk[j]], 1);
            pbuf[p] = ss[j] | ((ds[j] - bk[j] * BNODES) << 17);
            bsl[p] = (unsigned char)bk[j];
        }
    }
    int cb = scanb[t + 1] - scanb[t];
    if (cb > 0) gbase[t] = atomicAdd(&bcur[t], cb);
    __syncthreads();
    for (int s = t; s < m; s += 256) {
        int b = bsl[s];
        pairs[gbase[b] + (s - scanb[b])] = pbuf[s];
    }
}

// pass 2: one block per bucket. LDS: hist -> scan -> deg/rs out, scatter -> csr out.
__global__ __launch_bounds__(256) void k_pass2(
    const int* __restrict__ pairs, const int* __restrict__ bbase,
    int* __restrict__ deg, int* __restrict__ rs, int* __restrict__ csr) {
    __shared__ int buf1[BUFCAP];
    __shared__ int buf2[BUFCAP];
    __shared__ int cnt[512];
    __shared__ int rsl[512];
    __shared__ int cur[512];
    __shared__ int s1[256];
    int b = blockIdx.x;
    int n0 = b * BNODES;
    if (n0 >= NN) return;
    int nlocal = NN - n0; if (nlocal > BNODES) nlocal = BNODES;
    int t = threadIdx.x;
    int base = bbase[b];
    int m = bbase[b + 1] - base;
    bool fits = (m <= BUFCAP);
    cnt[t] = 0; cnt[t + 256] = 0;
    __syncthreads();
    for (int s = t; s < m; s += 256) {
        int pk = pairs[base + s];
        if (fits) buf1[s] = pk;
        atomicAdd(&cnt[(uint)pk >> 17], 1);
    }
    __syncthreads();
    int c0 = cnt[2 * t], c1 = cnt[2 * t + 1];
    int ps = c0 + c1;
    s1[t] = ps;
    __syncthreads();
    for (int off = 1; off < 256; off <<= 1) {
        int u = (t >= off) ? s1[t - off] : 0;
        __syncthreads();
        s1[t] += u;
        __syncthreads();
    }
    int pexcl = s1[t] - ps;
    rsl[2 * t] = pexcl;          cur[2 * t] = pexcl;
    rsl[2 * t + 1] = pexcl + c0; cur[2 * t + 1] = pexcl + c0;
    __syncthreads();
    for (int i = t; i < nlocal; i += 256) {
        deg[n0 + i] = cnt[i];
        rs[n0 + i] = base + rsl[i];
    }
    if (fits) {
        for (int s = t; s < m; s += 256) {
            int pk = buf1[s];
            int p = atomicAdd(&cur[(uint)pk >> 17], 1);
            buf2[p] = pk & 0x1FFFF;
        }
        __syncthreads();
        for (int s = t; s < m; s += 256) csr[base + s] = buf2[s];
    } else {
        for (int s = t; s < m; s += 256) {
            int pk = pairs[base + s];
            int p = atomicAdd(&cur[(uint)pk >> 17], 1);
            csr[base + p] = pk & 0x1FFFF;
        }
    }
}

// ---------------- x prepack: [N,14] f32 -> [N,16] fp16 (8 uints/row) ----------------

__global__ void k_packx(const float* __restrict__ x, uint* __restrict__ xh) {
    int t = blockIdx.x * blockDim.x + threadIdx.x;
    if (t < NN * 8) {
        int row = t >> 3, q = t & 7;
        int j0 = 2 * q, j1 = 2 * q + 1;
        float f0 = (j0 < FIN) ? x[row * FIN + j0] : 0.f;
        float f1 = (j1 < FIN) ? x[row * FIN + j1] : 0.f;
        xh[t] = pkh(f0, f1);
    }
}

// ---------------- Layer 1: fp16 rows, packed-half accumulate ----------------

__global__ __launch_bounds__(256, 6) void k_layer1(
    const float* __restrict__ x, const uint* __restrict__ xh, uint* __restrict__ hout,
    const float* __restrict__ Wl, const float* __restrict__ Wr, const float* __restrict__ b,
    const int* __restrict__ rs, const int* __restrict__ deg, const int* __restrict__ csr) {
    __shared__ float2 sW[FIN][HD];
    __shared__ float sb[HD];
    __shared__ float2 sAH[4][16];
    for (int i = threadIdx.x; i < FIN * HD; i += 256) {
        int k = i >> 6, j = i & 63;
        sW[k][j] = make_float2(Wl[i], Wr[i]);
    }
    if (threadIdx.x < HD) sb[threadIdx.x] = b[threadIdx.x];
    __syncthreads();
    int lane = threadIdx.x & 63, wid = threadIdx.x >> 6;
    int sub = lane >> 3;     // edge slot 0..7
    int fq = lane & 7;       // uint index in row (features 2fq,2fq+1)
    int ngroups = (NN + 3) / 4;
    for (int g = blockIdx.x; g < ngroups; g += gridDim.x) {
        int n = g * 4 + wid;
        bool act = n < NN;
        if (act) {
            int s0 = rs[n], d = deg[n];
            float xv = (lane < FIN) ? x[n * FIN + lane] : 0.f;
            __half2 Z = __float2half2_rn(0.f);
            __half2 A0 = Z, A1 = Z, A2 = Z, A3 = Z, A4 = Z, A5 = Z, A6 = Z, A7 = Z;
            for (int base = 0; base < d; base += 64) {
                int rem = d - base; if (rem > 64) rem = 64;
                int idxv = (lane < rem) ? csr[s0 + base + lane] : 0;
                int j = 0;
                for (; j + 64 <= rem; j += 64) {
                    int i0 = __shfl(idxv, j + 0 + sub);
                    int i1 = __shfl(idxv, j + 8 + sub);
                    int i2 = __shfl(idxv, j + 16 + sub);
                    int i3 = __shfl(idxv, j + 24 + sub);
                    int i4 = __shfl(idxv, j + 32 + sub);
                    int i5 = __shfl(idxv, j + 40 + sub);
                    int i6 = __shfl(idxv, j + 48 + sub);
                    int i7 = __shfl(idxv, j + 56 + sub);
                    A0 = __hadd2(A0, u2h(xh[(size_t)i0 * 8 + fq]));
                    A1 = __hadd2(A1, u2h(xh[(size_t)i1 * 8 + fq]));
                    A2 = __hadd2(A2, u2h(xh[(size_t)i2 * 8 + fq]));
                    A3 = __hadd2(A3, u2h(xh[(size_t)i3 * 8 + fq]));
                    A4 = __hadd2(A4, u2h(xh[(size_t)i4 * 8 + fq]));
                    A5 = __hadd2(A5, u2h(xh[(size_t)i5 * 8 + fq]));
                    A6 = __hadd2(A6, u2h(xh[(size_t)i6 * 8 + fq]));
                    A7 = __hadd2(A7, u2h(xh[(size_t)i7 * 8 + fq]));
                }
                for (; j + 8 <= rem; j += 8) {
                    int i0 = __shfl(idxv, j + sub);
                    A0 = __hadd2(A0, u2h(xh[(size_t)i0 * 8 + fq]));
                }
                if (j < rem) {
                    int i0 = __shfl(idxv, j + sub);
                    if (sub < rem - j) A0 = __hadd2(A0, u2h(xh[(size_t)i0 * 8 + fq]));
                }
            }
            // pairwise fp16 combine, then f32
            A0 = __hadd2(A0, A1); A2 = __hadd2(A2, A3);
            A4 = __hadd2(A4, A5); A6 = __hadd2(A6, A7);
            A0 = __hadd2(A0, A2); A4 = __hadd2(A4, A6);
            A0 = __hadd2(A0, A4);
            float ax = __low2float(A0), ay = __high2float(A0);
            for (int off = 8; off <= 32; off <<= 1) {
                ax += __shfl_xor(ax, off);
                ay += __shfl_xor(ay, off);
            }
            float inv = 1.0f / (float)(d > 1 ? d : 1);
            float e0 = __shfl(ax, lane >> 1);
            float e1 = __shfl(ay, lane >> 1);
            float sel = (lane & 1) ? e1 : e0;
            if (lane < 16) sAH[wid][lane] = make_float2((lane < FIN) ? sel * inv : 0.f, xv);
        }
        // no barrier: sAH[wid] is per-wave scratch (same-wave LDS RAW ordered by lgkmcnt)
        float out = sb[lane];
#pragma unroll
        for (int k = 0; k < FIN; ++k) {
            float2 w = sW[k][lane];
            float2 ah = sAH[wid][k];
            out += ah.x * w.x + ah.y * w.y;
        }
        out = fmaxf(out, 0.f);
        float o2 = __shfl_xor(out, 1);
        if (act && !(lane & 1)) hout[(size_t)n * 32 + (lane >> 1)] = pkh(out, o2);
    }
}

// ---------------- H layers: fp16 gather with v_pk_add_f16, fp16-packed weights ----------------

template <bool FUSEZ>
__global__ __launch_bounds__(256, 6) void k_layerH(
    const uint* __restrict__ hin, uint* __restrict__ hout,
    const float* __restrict__ Wl, const float* __restrict__ Wr, const float* __restrict__ b,
    const float* __restrict__ W4l, float* __restrict__ z,
    const int* __restrict__ rs, const int* __restrict__ deg, const int* __restrict__ csr) {
    __shared__ uint sWp[HD][HD];        // {Wl,Wr} packed fp16: 16 KB
    __shared__ float sb[HD], sW4l[HD * NC];
    __shared__ float2 sAH[4][HD];       // per-wave scratch
    for (int i = threadIdx.x; i < HD * HD; i += 256) {
        int k = i >> 6, j = i & 63;
        sWp[k][j] = pkh(Wl[i], Wr[i]);
    }
    if (threadIdx.x < HD) sb[threadIdx.x] = b[threadIdx.x];
    if (FUSEZ && threadIdx.x < HD * NC) sW4l[threadIdx.x] = W4l[threadIdx.x];
    __syncthreads();
    const uint2* hb2 = (const uint2*)hin;
    int lane = threadIdx.x & 63, wid = threadIdx.x >> 6;
    int sub = lane >> 4;       // edge slot 0..3
    int fq = lane & 15;        // uint2 index in row (features 4fq..4fq+3)
    int ngroups = (NN + 3) / 4;
    for (int g = blockIdx.x; g < ngroups; g += gridDim.x) {
        int n = g * 4 + wid;
        bool act = n < NN;
        if (act) {
            int s0 = rs[n], d = deg[n];
            __half2 hh = u2h(hin[(size_t)n * 32 + (lane >> 1)]);   // self feature, hoisted
            float hv = (lane & 1) ? __high2float(hh) : __low2float(hh);
            __half2 Zh = __float2half2_rn(0.f);
            __half2 P0 = Zh, P1 = Zh, P2 = Zh, P3 = Zh, P4 = Zh, P5 = Zh, P6 = Zh, P7 = Zh;
            __half2 Q0 = Zh, Q1 = Zh, Q2 = Zh, Q3 = Zh, Q4 = Zh, Q5 = Zh, Q6 = Zh, Q7 = Zh;
            for (int base = 0; base < d; base += 64) {
                int rem = d - base; if (rem > 64) rem = 64;
                int idxv = (lane < rem) ? csr[s0 + base + lane] : 0;
                int j = 0;
                for (; j + 32 <= rem; j += 32) {
                    int i0 = __shfl(idxv, j + 0 + sub);
                    int i1 = __shfl(idxv, j + 4 + sub);
                    int i2 = __shfl(idxv, j + 8 + sub);
                    int i3 = __shfl(idxv, j + 12 + sub);
                    int i4 = __shfl(idxv, j + 16 + sub);
                    int i5 = __shfl(idxv, j + 20 + sub);
                    int i6 = __shfl(idxv, j + 24 + sub);
                    int i7 = __shfl(idxv, j + 28 + sub);
                    uint2 U;
                    U = hb2[(size_t)i0 * 16 + fq]; P0 = __hadd2(P0, u2h(U.x)); Q0 = __hadd2(Q0, u2h(U.y));
                    U = hb2[(size_t)i1 * 16 + fq]; P1 = __hadd2(P1, u2h(U.x)); Q1 = __hadd2(Q1, u2h(U.y));
                    U = hb2[(size_t)i2 * 16 + fq]; P2 = __hadd2(P2, u2h(U.x)); Q2 = __hadd2(Q2, u2h(U.y));
                    U = hb2[(size_t)i3 * 16 + fq]; P3 = __hadd2(P3, u2h(U.x)); Q3 = __hadd2(Q3, u2h(U.y));
                    U = hb2[(size_t)i4 * 16 + fq]; P4 = __hadd2(P4, u2h(U.x)); Q4 = __hadd2(Q4, u2h(U.y));
                    U = hb2[(size_t)i5 * 16 + fq]; P5 = __hadd2(P5, u2h(U.x)); Q5 = __hadd2(Q5, u2h(U.y));
                    U = hb2[(size_t)i6 * 16 + fq]; P6 = __hadd2(P6, u2h(U.x)); Q6 = __hadd2(Q6, u2h(U.y));
                    U = hb2[(size_t)i7 * 16 + fq]; P7 = __hadd2(P7, u2h(U.x)); Q7 = __hadd2(Q7, u2h(U.y));
                }
                for (; j + 4 <= rem; j += 4) {
                    int i0 = __shfl(idxv, j + sub);
                    uint2 U = hb2[(size_t)i0 * 16 + fq];
                    P0 = __hadd2(P0, u2h(U.x)); Q0 = __hadd2(Q0, u2h(U.y));
                }
                if (j < rem) {
                    int i0 = __shfl(idxv, j + sub);
                    if (sub < rem - j) {
                        uint2 U = hb2[(size_t)i0 * 16 + fq];
                        P0 = __hadd2(P0, u2h(U.x)); Q0 = __hadd2(Q0, u2h(U.y));
                    }
                }
            }
            // pairwise fp16 combine
            P0 = __hadd2(P0, P1); P2 = __hadd2(P2, P3);
            P4 = __hadd2(P4, P5); P6 = __hadd2(P6, P7);
            Q0 = __hadd2(Q0, Q1); Q2 = __hadd2(Q2, Q3);
            Q4 = __hadd2(Q4, Q5); Q6 = __hadd2(Q6, Q7);
            P0 = __hadd2(P0, P2); P4 = __hadd2(P4, P6);
            Q0 = __hadd2(Q0, Q2); Q4 = __hadd2(Q4, Q6);
            P0 = __hadd2(P0, P4); Q0 = __hadd2(Q0, Q4);
            float4 A0 = make_float4(__low2float(P0), __high2float(P0),
                                    __low2float(Q0), __high2float(Q0));
            for (int off = 16; off <= 32; off <<= 1) {
                A0.x += __shfl_xor(A0.x, off);
                A0.y += __shfl_xor(A0.y, off);
                A0.z += __shfl_xor(A0.z, off);
                A0.w += __shfl_xor(A0.w, off);
            }
            float inv = 1.0f / (float)(d > 1 ? d : 1);
            A0.x *= inv; A0.y *= inv; A0.z *= inv; A0.w *= inv;
            float e0 = __shfl(A0.x, lane >> 2);
            float e1 = __shfl(A0.y, lane >> 2);
            float e2 = __shfl(A0.z, lane >> 2);
            float e3 = __shfl(A0.w, lane >> 2);
            int c = lane & 3;
            float sel = (c == 0) ? e0 : (c == 1) ? e1 : (c == 2) ? e2 : e3;
            sAH[wid][lane] = make_float2(sel, hv);
        }
        // no barrier: sAH[wid] is per-wave scratch
        float out = sb[lane];
#pragma unroll 8
        for (int k = 0; k < HD; ++k) {
            __half2 wh = u2h(sWp[k][lane]);
            float2 ah = sAH[wid][k];
            out += ah.x * __low2float(wh) + ah.y * __high2float(wh);
        }
        out = fmaxf(out, 0.f);
        float o2 = __shfl_xor(out, 1);
        if (act && !(lane & 1)) hout[(size_t)n * 32 + (lane >> 1)] = pkh(out, o2);
        if (FUSEZ) {
            float r0 = out * sW4l[lane * NC + 0];
            float r1 = out * sW4l[lane * NC + 1];
            for (int off = 32; off; off >>= 1) {
                r0 += __shfl_xor(r0, off);
                r1 += __shfl_xor(r1, off);
            }
            if (act && lane == 0) ((float2*)z)[n] = make_float2(r0, r1);
        }
    }
}

// ---------------- Layer 4 + graph pooling sum ----------------

__global__ __launch_bounds__(256) void k_pool(
    const uint* __restrict__ h3, const float* __restrict__ z,
    const float* __restrict__ W4r, const float* __restrict__ b4,
    const int* __restrict__ rs, const int* __restrict__ deg, const int* __restrict__ csr,
    const int* __restrict__ batch, float* __restrict__ gsum) {
    __shared__ float sW[HD * NC];
    if (threadIdx.x < HD * NC) sW[threadIdx.x] = W4r[threadIdx.x];
    __syncthreads();
    const float2* z2 = (const float2*)z;
    int lane = threadIdx.x & 63, wid = threadIdx.x >> 6;
    int stride = gridDim.x * 4;
    for (int n = blockIdx.x * 4 + wid; n < NN; n += stride) {
        float r0 = 0.f, r1 = 0.f;
        if (lane < 32) {
            __half2 h = u2h(h3[(size_t)n * 32 + lane]);
            float f0 = __low2float(h), f1 = __high2float(h);
            r0 = f0 * sW[(2 * lane) * NC + 0] + f1 * sW[(2 * lane + 1) * NC + 0];
            r1 = f0 * sW[(2 * lane) * NC + 1] + f1 * sW[(2 * lane + 1) * NC + 1];
        }
        int s0 = rs[n], d = deg[n];
        float a0 = 0.f, a1 = 0.f;
        for (int j = lane; j < d; j += 64) {
            int s = csr[s0 + j];
            float2 zv = z2[s];
            a0 += zv.x;
            a1 += zv.y;
        }
        for (int off = 32; off; off >>= 1) {
            r0 += __shfl_xor(r0, off);
            r1 += __shfl_xor(r1, off);
            a0 += __shfl_xor(a0, off);
            a1 += __shfl_xor(a1, off);
        }
        if (lane == 0) {
            float inv = 1.0f / (float)(d > 1 ? d : 1);
            float o0 = a0 * inv + r0 + b4[0];
            float o1 = a1 * inv + r1 + b4[1];
            int gg = batch[n];
            atomicAdd(&gsum[gg * 2 + 0], o0);
            atomicAdd(&gsum[gg * 2 + 1], o1);
        }
    }
}

__global__ void k_final(const float* __restrict__ gsum, const int* __restrict__ gstart,
                        const int* __restrict__ gend, float* __restrict__ out) {
    int g = blockIdx.x * blockDim.x + threadIdx.x;
    if (g < NG) {
        int cnt = gend[g] - gstart[g];
        float inv = 1.0f / (float)(cnt > 1 ? cnt : 1);
        float p0 = gsum[g * 2 + 0] * inv;
        float p1 = gsum[g * 2 + 1] * inv;
        float m = fmaxf(p0, p1);
        float lse = m + logf(expf(p0 - m) + expf(p1 - m));
        out[g * 2 + 0] = p0 - lse;
        out[g * 2 + 1] = p1 - lse;
    }
}

// ---------------- launch ----------------

extern "C" void kernel_launch(void* const* d_in, const int* in_sizes, int n_in,
                              void* d_out, int out_size, void* d_ws, size_t ws_size,
                              hipStream_t stream) {
    const float* x   = (const float*)d_in[0];
    const float* W1l = (const float*)d_in[1];
    const float* W1r = (const float*)d_in[2];
    const float* b1  = (const float*)d_in[3];
    const float* W2l = (const float*)d_in[4];
    const float* W2r = (const float*)d_in[5];
    const float* b2  = (const float*)d_in[6];
    const float* W3l = (const float*)d_in[7];
    const float* W3r = (const float*)d_in[8];
    const float* b3  = (const float*)d_in[9];
    const float* W4l = (const float*)d_in[10];
    const float* W4r = (const float*)d_in[11];
    const float* b4  = (const float*)d_in[12];
    const int* ei    = (const int*)d_in[13];
    const int* batch = (const int*)d_in[14];
    const int* src = ei;
    const int* dst = ei + NE;
    float* out = (float*)d_out;

    char* w = (char*)d_ws;
    int* deg    = (int*)w; w += (size_t)NN * 4;
    int* rs     = (int*)w; w += (size_t)NN * 4;
    int* csr    = (int*)w; w += (size_t)NE * 4;
    int* gstart = (int*)w; w += (size_t)NG * 4;
    int* gend   = (int*)w; w += (size_t)NG * 4;
    int* bkcnt  = (int*)w; w += NBUK * 4;
    int* bbase  = (int*)w; w += (NBUK + 1) * 4;
    int* bcur   = (int*)w; w += NBUK * 4;
    w = (char*)(((uintptr_t)w + 255) & ~(uintptr_t)255);
    uint* xh    = (uint*)w; w += (size_t)NN * 8 * 4;
    uint* hA    = (uint*)w; w += (size_t)NN * 32 * 4;
    uint* hB    = (uint*)w; w += (size_t)NN * 32 * 4;
    float* z    = (float*)w; w += (size_t)NN * NC * 4;
    float* gsum = (float*)w; w += (size_t)NG * NC * 4;
    int* pairs = (int*)hB;  // alias: NE*4 == NN*32*4 bytes; dead before layer 2 writes hB

    const int P1B = (NE + P1E - 1) / P1E;  // 782

    hipMemsetAsync(bkcnt, 0, NBUK * 4, stream);
    hipMemsetAsync(gstart, 0, (size_t)NG * 4, stream);
    hipMemsetAsync(gend, 0, (size_t)NG * 4, stream);
    hipMemsetAsync(gsum, 0, (size_t)NG * NC * 4, stream);

    k_hist_bucket<<<P1B, 256, 0, stream>>>(dst, bkcnt);
    k_packx<<<(NN * 8 + 255) / 256, 256, 0, stream>>>(x, xh);
    k_gbounds<<<(NN + 255) / 256, 256, 0, stream>>>(batch, gstart, gend);
    k_scanb<<<1, NBUK, 0, stream>>>(bkcnt, bbase, bcur);
    k_pass1<<<P1B, 256, 0, stream>>>(src, dst, bcur, pairs);
    k_pass2<<<NBUK, 256, 0, stream>>>(pairs, bbase, deg, rs, csr);

    k_layer1<<<1536, 256, 0, stream>>>(x, xh, hA, W1l, W1r, b1, rs, deg, csr);
    k_layerH<false><<<1536, 256, 0, stream>>>(hA, hB, W2l, W2r, b2, nullptr, nullptr, rs, deg, csr);
    k_layerH<true><<<1536, 256, 0, stream>>>(hB, hA, W3l, W3r, b3, W4l, z, rs, deg, csr);
    k_pool<<<2048, 256, 0, stream>>>(hA, z, W4r, b4, rs, deg, csr, batch, gsum);
    k_final<<<(NG + 255) / 256, 256, 0, stream>>>(gsum, gstart, gend, out);
}